// Round 5
// baseline (505.533 us; speedup 1.0000x reference)
//
#include <hip/hip_runtime.h>
#include <math.h>

#define ALPHA 0.5f
#define BETA 0.9f
#define Bsz 512
#define Tsz 512
#define Dsz 256

__device__ __forceinline__ float wave_reduce_sum(float v) {
    v += __shfl_xor(v, 32, 64);
    v += __shfl_xor(v, 16, 64);
    v += __shfl_xor(v, 8, 64);
    v += __shfl_xor(v, 4, 64);
    v += __shfl_xor(v, 2, 64);
    v += __shfl_xor(v, 1, 64);
    return v;
}

__device__ __forceinline__ float wave_reduce_max(float v) {
    v = fmaxf(v, __shfl_xor(v, 32, 64));
    v = fmaxf(v, __shfl_xor(v, 16, 64));
    v = fmaxf(v, __shfl_xor(v, 8, 64));
    v = fmaxf(v, __shfl_xor(v, 4, 64));
    v = fmaxf(v, __shfl_xor(v, 2, 64));
    v = fmaxf(v, __shfl_xor(v, 1, 64));
    return v;
}

// Fused kernel, 512 threads (8 waves) per block, one block per batch row.
//   phase 0: ts/pad -> ok, tmax, count, lam
//   phase 1: ascending-t stream over x[b] -> mean-pooled q
//   phase 2: Q = q@WQ.T ; qk = (Q@WK)/16
//   phase 3: SINGLE-READ per-wave pass: lane (rloc,sub) holds row r's chunks {8jj+sub},
//            uses them for both the score dot and the g-weighted accumulation
//            (acc[jj] = partial of xw chunk 8jj+sub). 8 loads in flight per wave
//            (register budget ~110 <= 128 cap from __launch_bounds__(512,4)).
//   phase 4: L = WV@xw, delta, M, T_event, p
__global__ __launch_bounds__(512, 4) void fused(const float* __restrict__ x,
                                                const float* __restrict__ ts,
                                                const unsigned char* __restrict__ pad,
                                                const float* __restrict__ WQ,
                                                const float* __restrict__ WK,
                                                const float* __restrict__ WV,
                                                const float* __restrict__ prevL,
                                                const float* __restrict__ prevM,
                                                const float* __restrict__ clsw,
                                                const float* __restrict__ clsb,
                                                float* __restrict__ out) {
    const int b = blockIdx.x;
    const int tid = threadIdx.x;
    const int w = tid >> 6, lane = tid & 63;
    const int rloc = lane >> 3;             // 0..7: row within this wave's 8-row group
    const int sub = lane & 7;               // 0..7: chunk-set owner (chunks {8jj+sub})

    __shared__ float lamS[Tsz];             // phase 0: raw ts; then lam
    __shared__ float okS[Tsz];
    __shared__ __align__(16) float part[8][Dsz];  // q partials / GEMV halves / acc partials
    __shared__ float qS[Dsz];
    __shared__ float QS[Dsz];
    __shared__ __align__(16) float qkS[Dsz];
    __shared__ float xwS[Dsz];
    __shared__ float EGS[16];
    __shared__ float red[16];
    __shared__ float red2[8];
    __shared__ float tmaxS, cntS;

    // ---- phase 0a: one t per thread ----
    {
        bool v = (pad[(size_t)b * Tsz + tid] == 0);
        float tv = ts[(size_t)b * Tsz + tid];
        okS[tid] = v ? 1.f : 0.f;
        lamS[tid] = tv;
        float lmax = v ? tv : -1e30f;
        float lcnt = v ? 1.f : 0.f;
        lmax = wave_reduce_max(lmax);
        lcnt = wave_reduce_sum(lcnt);
        if (lane == 0) { red[w] = lmax; red[8 + w] = lcnt; }
    }
    __syncthreads();
    if (tid == 0) {
        float m = -1e30f, c = 0.f;
        #pragma unroll
        for (int i = 0; i < 8; ++i) { m = fmaxf(m, red[i]); c += red[8 + i]; }
        tmaxS = m;
        cntS = fmaxf(c, 1.f);
    }
    __syncthreads();
    // ---- phase 0b: lam in place (same thread owns its t) ----
    {
        float dt = fmaxf(tmaxS - lamS[tid], 0.f) * (1.f / 86400.f);
        lamS[tid] = okS[tid] * __expf(-ALPHA * dt);
    }

    // ---- phase 1: q-sum; wave w owns rows [w*64, w*64+64), 4-row ILP ----
    const float* xb = x + (size_t)b * Tsz * Dsz;
    {
        float4 a0 = make_float4(0.f, 0.f, 0.f, 0.f);
        float4 a1 = a0, a2 = a0, a3 = a0;
        const int tbase = w * 64;
        for (int i = 0; i < 64; i += 4) {
            const int t = tbase + i;
            float4 x0 = *(const float4*)(xb + (size_t)(t + 0) * Dsz + lane * 4);
            float4 x1 = *(const float4*)(xb + (size_t)(t + 1) * Dsz + lane * 4);
            float4 x2 = *(const float4*)(xb + (size_t)(t + 2) * Dsz + lane * 4);
            float4 x3 = *(const float4*)(xb + (size_t)(t + 3) * Dsz + lane * 4);
            const float v0 = okS[t], v1 = okS[t + 1], v2 = okS[t + 2], v3 = okS[t + 3];
            a0.x += v0 * x0.x; a0.y += v0 * x0.y; a0.z += v0 * x0.z; a0.w += v0 * x0.w;
            a1.x += v1 * x1.x; a1.y += v1 * x1.y; a1.z += v1 * x1.z; a1.w += v1 * x1.w;
            a2.x += v2 * x2.x; a2.y += v2 * x2.y; a2.z += v2 * x2.z; a2.w += v2 * x2.w;
            a3.x += v3 * x3.x; a3.y += v3 * x3.y; a3.z += v3 * x3.z; a3.w += v3 * x3.w;
        }
        part[w][lane * 4 + 0] = (a0.x + a1.x) + (a2.x + a3.x);
        part[w][lane * 4 + 1] = (a0.y + a1.y) + (a2.y + a3.y);
        part[w][lane * 4 + 2] = (a0.z + a1.z) + (a2.z + a3.z);
        part[w][lane * 4 + 3] = (a0.w + a1.w) + (a2.w + a3.w);
    }
    __syncthreads();
    if (tid < Dsz) {
        float s = 0.f;
        #pragma unroll
        for (int w2 = 0; w2 < 8; ++w2) s += part[w2][tid];
        qS[tid] = s / cntS;
    }
    __syncthreads();

    // ---- phase 2a: Q[i] = sum_d q[d]*WQ[i,d], split across two halves of d ----
    {
        const int i = tid & 255, half = tid >> 8;
        const float* wq = WQ + (size_t)i * Dsz + half * 128;
        const float* qh = qS + half * 128;
        float acc = 0.f;
        #pragma unroll 4
        for (int d4 = 0; d4 < 128; d4 += 4) {
            float4 wv = *(const float4*)(wq + d4);
            acc += wv.x * qh[d4] + wv.y * qh[d4 + 1] + wv.z * qh[d4 + 2] + wv.w * qh[d4 + 3];
        }
        part[half][i] = acc;
    }
    __syncthreads();
    if (tid < Dsz) QS[tid] = part[0][tid] + part[1][tid];
    __syncthreads();

    // ---- phase 2b: qk[d] = (sum_e Q[e]*WK[e,d])/16, split across two halves of e ----
    {
        const int d = tid & 255, half = tid >> 8;
        const int e0 = half * 128;
        float v0 = 0.f, v1 = 0.f, v2 = 0.f, v3 = 0.f;
        #pragma unroll 4
        for (int e = e0; e < e0 + 128; e += 4) {
            v0 += QS[e + 0] * WK[(size_t)(e + 0) * Dsz + d];
            v1 += QS[e + 1] * WK[(size_t)(e + 1) * Dsz + d];
            v2 += QS[e + 2] * WK[(size_t)(e + 2) * Dsz + d];
            v3 += QS[e + 3] * WK[(size_t)(e + 3) * Dsz + d];
        }
        part[half][d] = (v0 + v1) + (v2 + v3);
    }
    __syncthreads();
    if (tid < Dsz) qkS[tid] = (part[0][tid] + part[1][tid]) * 0.0625f;
    __syncthreads();

    // ---- phase 3: per-wave, single-read; wave w owns rows [w*64, w*64+64) ----
    float4 qkr[8];
    #pragma unroll
    for (int jj = 0; jj < 8; ++jj)
        qkr[jj] = *(const float4*)(&qkS[(jj * 8 + sub) << 2]);

    float4 acc0 = make_float4(0.f, 0.f, 0.f, 0.f);
    float4 acc1 = acc0, acc2 = acc0, acc3 = acc0, acc4 = acc0, acc5 = acc0, acc6 = acc0, acc7 = acc0;
    float E = 0.f, G = 0.f;   // each row counted 8x (identical across subs); /8 at the end
    {
        const int rowbase = w * 64;
        for (int gi = 7; gi >= 0; --gi) {          // descending within region (cache-warm tail)
            const int r = rowbase + gi * 8 + rloc;
            const float* rp = xb + (size_t)r * Dsz;
            // one read of the row, kept live: xv[jj] = chunks {8jj+sub} of row r
            float4 xv0 = *(const float4*)(rp + ((0 * 8 + sub) << 2));
            float4 xv1 = *(const float4*)(rp + ((1 * 8 + sub) << 2));
            float4 xv2 = *(const float4*)(rp + ((2 * 8 + sub) << 2));
            float4 xv3 = *(const float4*)(rp + ((3 * 8 + sub) << 2));
            float4 xv4 = *(const float4*)(rp + ((4 * 8 + sub) << 2));
            float4 xv5 = *(const float4*)(rp + ((5 * 8 + sub) << 2));
            float4 xv6 = *(const float4*)(rp + ((6 * 8 + sub) << 2));
            float4 xv7 = *(const float4*)(rp + ((7 * 8 + sub) << 2));
            float s = xv0.x * qkr[0].x + xv0.y * qkr[0].y + xv0.z * qkr[0].z + xv0.w * qkr[0].w
                    + xv1.x * qkr[1].x + xv1.y * qkr[1].y + xv1.z * qkr[1].z + xv1.w * qkr[1].w
                    + xv2.x * qkr[2].x + xv2.y * qkr[2].y + xv2.z * qkr[2].z + xv2.w * qkr[2].w
                    + xv3.x * qkr[3].x + xv3.y * qkr[3].y + xv3.z * qkr[3].z + xv3.w * qkr[3].w
                    + xv4.x * qkr[4].x + xv4.y * qkr[4].y + xv4.z * qkr[4].z + xv4.w * qkr[4].w
                    + xv5.x * qkr[5].x + xv5.y * qkr[5].y + xv5.z * qkr[5].z + xv5.w * qkr[5].w
                    + xv6.x * qkr[6].x + xv6.y * qkr[6].y + xv6.z * qkr[6].z + xv6.w * qkr[6].w
                    + xv7.x * qkr[7].x + xv7.y * qkr[7].y + xv7.z * qkr[7].z + xv7.w * qkr[7].w;
            s += __shfl_xor(s, 1, 64);
            s += __shfl_xor(s, 2, 64);
            s += __shfl_xor(s, 4, 64);
            const float e = okS[r] * __expf(s);
            const float g = lamS[r] * e;
            E += e; G += g;
            acc0.x += g * xv0.x; acc0.y += g * xv0.y; acc0.z += g * xv0.z; acc0.w += g * xv0.w;
            acc1.x += g * xv1.x; acc1.y += g * xv1.y; acc1.z += g * xv1.z; acc1.w += g * xv1.w;
            acc2.x += g * xv2.x; acc2.y += g * xv2.y; acc2.z += g * xv2.z; acc2.w += g * xv2.w;
            acc3.x += g * xv3.x; acc3.y += g * xv3.y; acc3.z += g * xv3.z; acc3.w += g * xv3.w;
            acc4.x += g * xv4.x; acc4.y += g * xv4.y; acc4.z += g * xv4.z; acc4.w += g * xv4.w;
            acc5.x += g * xv5.x; acc5.y += g * xv5.y; acc5.z += g * xv5.z; acc5.w += g * xv5.w;
            acc6.x += g * xv6.x; acc6.y += g * xv6.y; acc6.z += g * xv6.z; acc6.w += g * xv6.w;
            acc7.x += g * xv7.x; acc7.y += g * xv7.y; acc7.z += g * xv7.z; acc7.w += g * xv7.w;
        }
    }
    // reduce acc[jj] across the 8 rloc groups (lanes differing in bits 3..5)
    #pragma unroll
    for (int step = 8; step <= 32; step <<= 1) {
        acc0.x += __shfl_xor(acc0.x, step, 64); acc0.y += __shfl_xor(acc0.y, step, 64);
        acc0.z += __shfl_xor(acc0.z, step, 64); acc0.w += __shfl_xor(acc0.w, step, 64);
        acc1.x += __shfl_xor(acc1.x, step, 64); acc1.y += __shfl_xor(acc1.y, step, 64);
        acc1.z += __shfl_xor(acc1.z, step, 64); acc1.w += __shfl_xor(acc1.w, step, 64);
        acc2.x += __shfl_xor(acc2.x, step, 64); acc2.y += __shfl_xor(acc2.y, step, 64);
        acc2.z += __shfl_xor(acc2.z, step, 64); acc2.w += __shfl_xor(acc2.w, step, 64);
        acc3.x += __shfl_xor(acc3.x, step, 64); acc3.y += __shfl_xor(acc3.y, step, 64);
        acc3.z += __shfl_xor(acc3.z, step, 64); acc3.w += __shfl_xor(acc3.w, step, 64);
        acc4.x += __shfl_xor(acc4.x, step, 64); acc4.y += __shfl_xor(acc4.y, step, 64);
        acc4.z += __shfl_xor(acc4.z, step, 64); acc4.w += __shfl_xor(acc4.w, step, 64);
        acc5.x += __shfl_xor(acc5.x, step, 64); acc5.y += __shfl_xor(acc5.y, step, 64);
        acc5.z += __shfl_xor(acc5.z, step, 64); acc5.w += __shfl_xor(acc5.w, step, 64);
        acc6.x += __shfl_xor(acc6.x, step, 64); acc6.y += __shfl_xor(acc6.y, step, 64);
        acc6.z += __shfl_xor(acc6.z, step, 64); acc6.w += __shfl_xor(acc6.w, step, 64);
        acc7.x += __shfl_xor(acc7.x, step, 64); acc7.y += __shfl_xor(acc7.y, step, 64);
        acc7.z += __shfl_xor(acc7.z, step, 64); acc7.w += __shfl_xor(acc7.w, step, 64);
    }
    if (rloc == 0) {   // 8 lanes (sub=0..7) hold the wave-total for chunks {8jj+sub}
        *(float4*)&part[w][(0 * 8 + sub) << 2] = acc0;
        *(float4*)&part[w][(1 * 8 + sub) << 2] = acc1;
        *(float4*)&part[w][(2 * 8 + sub) << 2] = acc2;
        *(float4*)&part[w][(3 * 8 + sub) << 2] = acc3;
        *(float4*)&part[w][(4 * 8 + sub) << 2] = acc4;
        *(float4*)&part[w][(5 * 8 + sub) << 2] = acc5;
        *(float4*)&part[w][(6 * 8 + sub) << 2] = acc6;
        *(float4*)&part[w][(7 * 8 + sub) << 2] = acc7;
    }
    {
        float Ew = wave_reduce_sum(E) * 0.125f;
        float Gw = wave_reduce_sum(G) * 0.125f;
        if (lane == 0) { EGS[w] = Ew; EGS[8 + w] = Gw; }
    }
    __syncthreads();
    if (tid < Dsz) {
        float Et = 0.f, Gt = 0.f;
        #pragma unroll
        for (int i = 0; i < 8; ++i) { Et += EGS[i]; Gt += EGS[8 + i]; }
        float denom = Gt + 1e-8f * Et;   // softmax denominators cancel
        float accd = 0.f;
        #pragma unroll
        for (int w2 = 0; w2 < 8; ++w2) accd += part[w2][tid];
        xwS[tid] = (denom > 0.f) ? accd / denom : 0.f;
    }
    __syncthreads();

    // ---- phase 4: Le[i] = sum_d WV[i,d]*xw[d], split halves; then delta/M/p ----
    {
        const int i = tid & 255, half = tid >> 8;
        const float* wv = WV + (size_t)i * Dsz + half * 128;
        const float* xh = xwS + half * 128;
        float a = 0.f;
        #pragma unroll 4
        for (int d4 = 0; d4 < 128; d4 += 4) {
            float4 wvv = *(const float4*)(wv + d4);
            a += wvv.x * xh[d4] + wvv.y * xh[d4 + 1] + wvv.z * xh[d4 + 2] + wvv.w * xh[d4 + 3];
        }
        part[half][i] = a;
    }
    __syncthreads();

    float Le = 0.f, delta = 0.f, pp = 0.f;
    if (tid < Dsz) {
        Le = part[0][tid] + part[1][tid];
        delta = Le - prevL[(size_t)b * Dsz + tid];
        pp = Le * clsw[tid] + delta * clsw[Dsz + tid];
    }
    float ssq = wave_reduce_sum(delta * delta);   // waves 4..7 contribute 0
    float psum = wave_reduce_sum(pp);
    if (lane == 0) { red[w] = ssq; red2[w] = psum; }
    __syncthreads();

    if (tid < Dsz) {
        float sr = 0.f;
        #pragma unroll
        for (int i = 0; i < 8; ++i) sr += red[i];
        float nrm = sqrtf(sr);
        float M = BETA * prevM[b] + (1.f - BETA) * nrm;

        float* out_p = out;
        float* out_T = out + Bsz;
        float* out_L = out + Bsz + (size_t)Bsz * (2 * Dsz + 1);
        float* out_M = out + Bsz + (size_t)Bsz * (2 * Dsz + 1) + (size_t)Bsz * Dsz;

        out_T[(size_t)b * (2 * Dsz + 1) + tid] = Le;
        out_T[(size_t)b * (2 * Dsz + 1) + Dsz + tid] = delta;
        out_L[(size_t)b * Dsz + tid] = Le;
        if (tid == 0) {
            float ps = 0.f;
            #pragma unroll
            for (int i = 0; i < 8; ++i) ps += red2[i];
            float p = ps + M * clsw[2 * Dsz] + clsb[0];
            out_p[b] = p;
            out_T[(size_t)b * (2 * Dsz + 1) + 2 * Dsz] = M;
            out_M[b] = M;
        }
    }
}

extern "C" void kernel_launch(void* const* d_in, const int* in_sizes, int n_in,
                              void* d_out, int out_size, void* d_ws, size_t ws_size,
                              hipStream_t stream) {
    const float* x     = (const float*)d_in[0];
    const float* ts    = (const float*)d_in[1];
    const float* prevL = (const float*)d_in[2];
    const float* prevM = (const float*)d_in[3];
    const unsigned char* pad = (const unsigned char*)d_in[4];
    const float* WQ    = (const float*)d_in[5];
    const float* WK    = (const float*)d_in[6];
    const float* WV    = (const float*)d_in[7];
    const float* clsw  = (const float*)d_in[8];
    const float* clsb  = (const float*)d_in[9];

    (void)d_ws; (void)ws_size;  // fully fused: no workspace needed

    fused<<<Bsz, 512, 0, stream>>>(x, ts, pad, WQ, WK, WV, prevL, prevM, clsw, clsb,
                                   (float*)d_out);
}

// Round 6
// 458.053 us; speedup vs baseline: 1.1037x; 1.1037x over previous
//
#include <hip/hip_runtime.h>
#include <math.h>

#define ALPHA 0.5f
#define BETA 0.9f
#define Bsz 512
#define Tsz 512
#define Dsz 256

__device__ __forceinline__ float wave_reduce_sum(float v) {
    v += __shfl_xor(v, 32, 64);
    v += __shfl_xor(v, 16, 64);
    v += __shfl_xor(v, 8, 64);
    v += __shfl_xor(v, 4, 64);
    v += __shfl_xor(v, 2, 64);
    v += __shfl_xor(v, 1, 64);
    return v;
}

__device__ __forceinline__ float wave_reduce_max(float v) {
    v = fmaxf(v, __shfl_xor(v, 32, 64));
    v = fmaxf(v, __shfl_xor(v, 16, 64));
    v = fmaxf(v, __shfl_xor(v, 8, 64));
    v = fmaxf(v, __shfl_xor(v, 4, 64));
    v = fmaxf(v, __shfl_xor(v, 2, 64));
    v = fmaxf(v, __shfl_xor(v, 1, 64));
    return v;
}

// Fused kernel, 512 threads (8 waves) per block, one block per batch row.
// __launch_bounds__(512, 2): on this hipcc the 2nd arg acts as workgroups/CU
// (round-4/5 evidence: (512,4) forced a 64-VGPR cap = 32 waves/CU and spilled
// 173 MB to scratch). (512,2) -> 16 waves/CU -> 128-VGPR cap; phase 3 needs
// ~110 regs (qkr 32 + xv 32 + acc 32 + addressing) -> no spill, and the grid
// (512 blocks x 8 waves / 256 CU) supplies exactly 16 waves/CU anyway.
__global__ __launch_bounds__(512, 2) void fused(const float* __restrict__ x,
                                                const float* __restrict__ ts,
                                                const unsigned char* __restrict__ pad,
                                                const float* __restrict__ WQ,
                                                const float* __restrict__ WK,
                                                const float* __restrict__ WV,
                                                const float* __restrict__ prevL,
                                                const float* __restrict__ prevM,
                                                const float* __restrict__ clsw,
                                                const float* __restrict__ clsb,
                                                float* __restrict__ out) {
    const int b = blockIdx.x;
    const int tid = threadIdx.x;
    const int w = tid >> 6, lane = tid & 63;
    const int rloc = lane >> 3;             // 0..7: row within this wave's 8-row group
    const int sub = lane & 7;               // 0..7: chunk-set owner (chunks {8jj+sub})

    __shared__ float lamS[Tsz];             // phase 0: raw ts; then lam
    __shared__ float okS[Tsz];
    __shared__ __align__(16) float part[8][Dsz];  // q partials / GEMV halves / acc partials
    __shared__ float qS[Dsz];
    __shared__ float QS[Dsz];
    __shared__ __align__(16) float qkS[Dsz];
    __shared__ float xwS[Dsz];
    __shared__ float EGS[16];
    __shared__ float red[16];
    __shared__ float red2[8];
    __shared__ float tmaxS, cntS;

    // ---- phase 0a: one t per thread ----
    {
        bool v = (pad[(size_t)b * Tsz + tid] == 0);
        float tv = ts[(size_t)b * Tsz + tid];
        okS[tid] = v ? 1.f : 0.f;
        lamS[tid] = tv;
        float lmax = v ? tv : -1e30f;
        float lcnt = v ? 1.f : 0.f;
        lmax = wave_reduce_max(lmax);
        lcnt = wave_reduce_sum(lcnt);
        if (lane == 0) { red[w] = lmax; red[8 + w] = lcnt; }
    }
    __syncthreads();
    if (tid == 0) {
        float m = -1e30f, c = 0.f;
        #pragma unroll
        for (int i = 0; i < 8; ++i) { m = fmaxf(m, red[i]); c += red[8 + i]; }
        tmaxS = m;
        cntS = fmaxf(c, 1.f);
    }
    __syncthreads();
    // ---- phase 0b: lam in place (same thread owns its t) ----
    {
        float dt = fmaxf(tmaxS - lamS[tid], 0.f) * (1.f / 86400.f);
        lamS[tid] = okS[tid] * __expf(-ALPHA * dt);
    }

    // ---- phase 1: q-sum; wave w owns rows [w*64, w*64+64), 4-row ILP ----
    const float* xb = x + (size_t)b * Tsz * Dsz;
    {
        float4 a0 = make_float4(0.f, 0.f, 0.f, 0.f);
        float4 a1 = a0, a2 = a0, a3 = a0;
        const int tbase = w * 64;
        for (int i = 0; i < 64; i += 4) {
            const int t = tbase + i;
            float4 x0 = *(const float4*)(xb + (size_t)(t + 0) * Dsz + lane * 4);
            float4 x1 = *(const float4*)(xb + (size_t)(t + 1) * Dsz + lane * 4);
            float4 x2 = *(const float4*)(xb + (size_t)(t + 2) * Dsz + lane * 4);
            float4 x3 = *(const float4*)(xb + (size_t)(t + 3) * Dsz + lane * 4);
            const float v0 = okS[t], v1 = okS[t + 1], v2 = okS[t + 2], v3 = okS[t + 3];
            a0.x += v0 * x0.x; a0.y += v0 * x0.y; a0.z += v0 * x0.z; a0.w += v0 * x0.w;
            a1.x += v1 * x1.x; a1.y += v1 * x1.y; a1.z += v1 * x1.z; a1.w += v1 * x1.w;
            a2.x += v2 * x2.x; a2.y += v2 * x2.y; a2.z += v2 * x2.z; a2.w += v2 * x2.w;
            a3.x += v3 * x3.x; a3.y += v3 * x3.y; a3.z += v3 * x3.z; a3.w += v3 * x3.w;
        }
        part[w][lane * 4 + 0] = (a0.x + a1.x) + (a2.x + a3.x);
        part[w][lane * 4 + 1] = (a0.y + a1.y) + (a2.y + a3.y);
        part[w][lane * 4 + 2] = (a0.z + a1.z) + (a2.z + a3.z);
        part[w][lane * 4 + 3] = (a0.w + a1.w) + (a2.w + a3.w);
    }
    __syncthreads();
    if (tid < Dsz) {
        float s = 0.f;
        #pragma unroll
        for (int w2 = 0; w2 < 8; ++w2) s += part[w2][tid];
        qS[tid] = s / cntS;
    }
    __syncthreads();

    // ---- phase 2a: Q[i] = sum_d q[d]*WQ[i,d], split across two halves of d ----
    {
        const int i = tid & 255, half = tid >> 8;
        const float* wq = WQ + (size_t)i * Dsz + half * 128;
        const float* qh = qS + half * 128;
        float acc = 0.f;
        #pragma unroll 4
        for (int d4 = 0; d4 < 128; d4 += 4) {
            float4 wv = *(const float4*)(wq + d4);
            acc += wv.x * qh[d4] + wv.y * qh[d4 + 1] + wv.z * qh[d4 + 2] + wv.w * qh[d4 + 3];
        }
        part[half][i] = acc;
    }
    __syncthreads();
    if (tid < Dsz) QS[tid] = part[0][tid] + part[1][tid];
    __syncthreads();

    // ---- phase 2b: qk[d] = (sum_e Q[e]*WK[e,d])/16, split across two halves of e ----
    {
        const int d = tid & 255, half = tid >> 8;
        const int e0 = half * 128;
        float v0 = 0.f, v1 = 0.f, v2 = 0.f, v3 = 0.f;
        #pragma unroll 4
        for (int e = e0; e < e0 + 128; e += 4) {
            v0 += QS[e + 0] * WK[(size_t)(e + 0) * Dsz + d];
            v1 += QS[e + 1] * WK[(size_t)(e + 1) * Dsz + d];
            v2 += QS[e + 2] * WK[(size_t)(e + 2) * Dsz + d];
            v3 += QS[e + 3] * WK[(size_t)(e + 3) * Dsz + d];
        }
        part[half][d] = (v0 + v1) + (v2 + v3);
    }
    __syncthreads();
    if (tid < Dsz) qkS[tid] = (part[0][tid] + part[1][tid]) * 0.0625f;
    __syncthreads();

    // ---- phase 3: per-wave, single-read; wave w owns rows [w*64, w*64+64) ----
    float4 qkr[8];
    #pragma unroll
    for (int jj = 0; jj < 8; ++jj)
        qkr[jj] = *(const float4*)(&qkS[(jj * 8 + sub) << 2]);

    float4 acc0 = make_float4(0.f, 0.f, 0.f, 0.f);
    float4 acc1 = acc0, acc2 = acc0, acc3 = acc0, acc4 = acc0, acc5 = acc0, acc6 = acc0, acc7 = acc0;
    float E = 0.f, G = 0.f;   // each row counted 8x (identical across subs); /8 at the end
    {
        const int rowbase = w * 64;
        for (int gi = 7; gi >= 0; --gi) {          // descending within region (cache-warm tail)
            const int r = rowbase + gi * 8 + rloc;
            const float* rp = xb + (size_t)r * Dsz;
            // one read of the row, kept live: xv[jj] = chunks {8jj+sub} of row r
            float4 xv0 = *(const float4*)(rp + ((0 * 8 + sub) << 2));
            float4 xv1 = *(const float4*)(rp + ((1 * 8 + sub) << 2));
            float4 xv2 = *(const float4*)(rp + ((2 * 8 + sub) << 2));
            float4 xv3 = *(const float4*)(rp + ((3 * 8 + sub) << 2));
            float4 xv4 = *(const float4*)(rp + ((4 * 8 + sub) << 2));
            float4 xv5 = *(const float4*)(rp + ((5 * 8 + sub) << 2));
            float4 xv6 = *(const float4*)(rp + ((6 * 8 + sub) << 2));
            float4 xv7 = *(const float4*)(rp + ((7 * 8 + sub) << 2));
            float s = xv0.x * qkr[0].x + xv0.y * qkr[0].y + xv0.z * qkr[0].z + xv0.w * qkr[0].w
                    + xv1.x * qkr[1].x + xv1.y * qkr[1].y + xv1.z * qkr[1].z + xv1.w * qkr[1].w
                    + xv2.x * qkr[2].x + xv2.y * qkr[2].y + xv2.z * qkr[2].z + xv2.w * qkr[2].w
                    + xv3.x * qkr[3].x + xv3.y * qkr[3].y + xv3.z * qkr[3].z + xv3.w * qkr[3].w
                    + xv4.x * qkr[4].x + xv4.y * qkr[4].y + xv4.z * qkr[4].z + xv4.w * qkr[4].w
                    + xv5.x * qkr[5].x + xv5.y * qkr[5].y + xv5.z * qkr[5].z + xv5.w * qkr[5].w
                    + xv6.x * qkr[6].x + xv6.y * qkr[6].y + xv6.z * qkr[6].z + xv6.w * qkr[6].w
                    + xv7.x * qkr[7].x + xv7.y * qkr[7].y + xv7.z * qkr[7].z + xv7.w * qkr[7].w;
            s += __shfl_xor(s, 1, 64);
            s += __shfl_xor(s, 2, 64);
            s += __shfl_xor(s, 4, 64);
            const float e = okS[r] * __expf(s);
            const float g = lamS[r] * e;
            E += e; G += g;
            acc0.x += g * xv0.x; acc0.y += g * xv0.y; acc0.z += g * xv0.z; acc0.w += g * xv0.w;
            acc1.x += g * xv1.x; acc1.y += g * xv1.y; acc1.z += g * xv1.z; acc1.w += g * xv1.w;
            acc2.x += g * xv2.x; acc2.y += g * xv2.y; acc2.z += g * xv2.z; acc2.w += g * xv2.w;
            acc3.x += g * xv3.x; acc3.y += g * xv3.y; acc3.z += g * xv3.z; acc3.w += g * xv3.w;
            acc4.x += g * xv4.x; acc4.y += g * xv4.y; acc4.z += g * xv4.z; acc4.w += g * xv4.w;
            acc5.x += g * xv5.x; acc5.y += g * xv5.y; acc5.z += g * xv5.z; acc5.w += g * xv5.w;
            acc6.x += g * xv6.x; acc6.y += g * xv6.y; acc6.z += g * xv6.z; acc6.w += g * xv6.w;
            acc7.x += g * xv7.x; acc7.y += g * xv7.y; acc7.z += g * xv7.z; acc7.w += g * xv7.w;
        }
    }
    // reduce acc[jj] across the 8 rloc groups (lanes differing in bits 3..5)
    #pragma unroll
    for (int step = 8; step <= 32; step <<= 1) {
        acc0.x += __shfl_xor(acc0.x, step, 64); acc0.y += __shfl_xor(acc0.y, step, 64);
        acc0.z += __shfl_xor(acc0.z, step, 64); acc0.w += __shfl_xor(acc0.w, step, 64);
        acc1.x += __shfl_xor(acc1.x, step, 64); acc1.y += __shfl_xor(acc1.y, step, 64);
        acc1.z += __shfl_xor(acc1.z, step, 64); acc1.w += __shfl_xor(acc1.w, step, 64);
        acc2.x += __shfl_xor(acc2.x, step, 64); acc2.y += __shfl_xor(acc2.y, step, 64);
        acc2.z += __shfl_xor(acc2.z, step, 64); acc2.w += __shfl_xor(acc2.w, step, 64);
        acc3.x += __shfl_xor(acc3.x, step, 64); acc3.y += __shfl_xor(acc3.y, step, 64);
        acc3.z += __shfl_xor(acc3.z, step, 64); acc3.w += __shfl_xor(acc3.w, step, 64);
        acc4.x += __shfl_xor(acc4.x, step, 64); acc4.y += __shfl_xor(acc4.y, step, 64);
        acc4.z += __shfl_xor(acc4.z, step, 64); acc4.w += __shfl_xor(acc4.w, step, 64);
        acc5.x += __shfl_xor(acc5.x, step, 64); acc5.y += __shfl_xor(acc5.y, step, 64);
        acc5.z += __shfl_xor(acc5.z, step, 64); acc5.w += __shfl_xor(acc5.w, step, 64);
        acc6.x += __shfl_xor(acc6.x, step, 64); acc6.y += __shfl_xor(acc6.y, step, 64);
        acc6.z += __shfl_xor(acc6.z, step, 64); acc6.w += __shfl_xor(acc6.w, step, 64);
        acc7.x += __shfl_xor(acc7.x, step, 64); acc7.y += __shfl_xor(acc7.y, step, 64);
        acc7.z += __shfl_xor(acc7.z, step, 64); acc7.w += __shfl_xor(acc7.w, step, 64);
    }
    if (rloc == 0) {   // 8 lanes (sub=0..7) hold the wave-total for chunks {8jj+sub}
        *(float4*)&part[w][(0 * 8 + sub) << 2] = acc0;
        *(float4*)&part[w][(1 * 8 + sub) << 2] = acc1;
        *(float4*)&part[w][(2 * 8 + sub) << 2] = acc2;
        *(float4*)&part[w][(3 * 8 + sub) << 2] = acc3;
        *(float4*)&part[w][(4 * 8 + sub) << 2] = acc4;
        *(float4*)&part[w][(5 * 8 + sub) << 2] = acc5;
        *(float4*)&part[w][(6 * 8 + sub) << 2] = acc6;
        *(float4*)&part[w][(7 * 8 + sub) << 2] = acc7;
    }
    {
        float Ew = wave_reduce_sum(E) * 0.125f;
        float Gw = wave_reduce_sum(G) * 0.125f;
        if (lane == 0) { EGS[w] = Ew; EGS[8 + w] = Gw; }
    }
    __syncthreads();
    if (tid < Dsz) {
        float Et = 0.f, Gt = 0.f;
        #pragma unroll
        for (int i = 0; i < 8; ++i) { Et += EGS[i]; Gt += EGS[8 + i]; }
        float denom = Gt + 1e-8f * Et;   // softmax denominators cancel
        float accd = 0.f;
        #pragma unroll
        for (int w2 = 0; w2 < 8; ++w2) accd += part[w2][tid];
        xwS[tid] = (denom > 0.f) ? accd / denom : 0.f;
    }
    __syncthreads();

    // ---- phase 4: Le[i] = sum_d WV[i,d]*xw[d], split halves; then delta/M/p ----
    {
        const int i = tid & 255, half = tid >> 8;
        const float* wv = WV + (size_t)i * Dsz + half * 128;
        const float* xh = xwS + half * 128;
        float a = 0.f;
        #pragma unroll 4
        for (int d4 = 0; d4 < 128; d4 += 4) {
            float4 wvv = *(const float4*)(wv + d4);
            a += wvv.x * xh[d4] + wvv.y * xh[d4 + 1] + wvv.z * xh[d4 + 2] + wvv.w * xh[d4 + 3];
        }
        part[half][i] = a;
    }
    __syncthreads();

    float Le = 0.f, delta = 0.f, pp = 0.f;
    if (tid < Dsz) {
        Le = part[0][tid] + part[1][tid];
        delta = Le - prevL[(size_t)b * Dsz + tid];
        pp = Le * clsw[tid] + delta * clsw[Dsz + tid];
    }
    float ssq = wave_reduce_sum(delta * delta);   // waves 4..7 contribute 0
    float psum = wave_reduce_sum(pp);
    if (lane == 0) { red[w] = ssq; red2[w] = psum; }
    __syncthreads();

    if (tid < Dsz) {
        float sr = 0.f;
        #pragma unroll
        for (int i = 0; i < 8; ++i) sr += red[i];
        float nrm = sqrtf(sr);
        float M = BETA * prevM[b] + (1.f - BETA) * nrm;

        float* out_p = out;
        float* out_T = out + Bsz;
        float* out_L = out + Bsz + (size_t)Bsz * (2 * Dsz + 1);
        float* out_M = out + Bsz + (size_t)Bsz * (2 * Dsz + 1) + (size_t)Bsz * Dsz;

        out_T[(size_t)b * (2 * Dsz + 1) + tid] = Le;
        out_T[(size_t)b * (2 * Dsz + 1) + Dsz + tid] = delta;
        out_L[(size_t)b * Dsz + tid] = Le;
        if (tid == 0) {
            float ps = 0.f;
            #pragma unroll
            for (int i = 0; i < 8; ++i) ps += red2[i];
            float p = ps + M * clsw[2 * Dsz] + clsb[0];
            out_p[b] = p;
            out_T[(size_t)b * (2 * Dsz + 1) + 2 * Dsz] = M;
            out_M[b] = M;
        }
    }
}

extern "C" void kernel_launch(void* const* d_in, const int* in_sizes, int n_in,
                              void* d_out, int out_size, void* d_ws, size_t ws_size,
                              hipStream_t stream) {
    const float* x     = (const float*)d_in[0];
    const float* ts    = (const float*)d_in[1];
    const float* prevL = (const float*)d_in[2];
    const float* prevM = (const float*)d_in[3];
    const unsigned char* pad = (const unsigned char*)d_in[4];
    const float* WQ    = (const float*)d_in[5];
    const float* WK    = (const float*)d_in[6];
    const float* WV    = (const float*)d_in[7];
    const float* clsw  = (const float*)d_in[8];
    const float* clsb  = (const float*)d_in[9];

    (void)d_ws; (void)ws_size;  // fully fused: no workspace needed

    fused<<<Bsz, 512, 0, stream>>>(x, ts, pad, WQ, WK, WV, prevL, prevM, clsw, clsb,
                                   (float*)d_out);
}